// Round 10
// baseline (355.790 us; speedup 1.0000x reference)
//
#include <hip/hip_runtime.h>
#include <math.h>

// Problem constants: B=2, L=2048, E=1024, H=16, D=64
#define LQ 2048
#define EQ 1024
#define M_ROWS 4096
#define BH 32

typedef _Float16 f16x8 __attribute__((ext_vector_type(8)));
typedef _Float16 f16x4 __attribute__((ext_vector_type(4)));
typedef _Float16 f16x2 __attribute__((ext_vector_type(2)));
typedef float f32x4 __attribute__((ext_vector_type(4)));
typedef float f32x16 __attribute__((ext_vector_type(16)));

// 1/sqrt(64) * log2(e) -> softmax in exp2 domain (applied to combined q)
#define QSCALE 0.1803368801111204f

__device__ __forceinline__ void async_ld16(const _Float16* g, _Float16* l) {
  __builtin_amdgcn_global_load_lds(
      (const __attribute__((address_space(1))) unsigned int*)g,
      (__attribute__((address_space(3))) unsigned int*)l, 16, 0, 0);
}

// ---------------------------------------------------------------------------
// Prep (1 launch): blocks [0,4096) convert xt,xs fp32->fp16;
// blocks [4096,10240) transpose W fp32[k][n] -> WT fp16[n][k].
// ---------------------------------------------------------------------------
__global__ __launch_bounds__(256) void prep(
    const float* __restrict__ xt, const float* __restrict__ xs,
    const float* __restrict__ Wt, const float* __restrict__ Ws,
    const float* __restrict__ Wc,
    _Float16* __restrict__ xt16, _Float16* __restrict__ xs16,
    _Float16* __restrict__ WtT, _Float16* __restrict__ WsT,
    _Float16* __restrict__ WcT) {
  int gb = blockIdx.x;
  if (gb < 4096) {
    int i = gb * 256 + threadIdx.x;
    const float* s; _Float16* d; size_t off;
    if (i < 524288) { s = xt; d = xt16; off = (size_t)i * 8; }
    else            { s = xs; d = xs16; off = (size_t)(i - 524288) * 8; }
    float4 a = *(const float4*)&s[off];
    float4 b = *(const float4*)&s[off + 4];
    f16x8 h;
    h[0] = (_Float16)a.x; h[1] = (_Float16)a.y; h[2] = (_Float16)a.z; h[3] = (_Float16)a.w;
    h[4] = (_Float16)b.x; h[5] = (_Float16)b.y; h[6] = (_Float16)b.z; h[7] = (_Float16)b.w;
    *(f16x8*)&d[off] = h;
  } else {
    __shared__ float T[32][33];
    int tb = gb - 4096;
    int tx = threadIdx.x & 31, ty = threadIdx.x >> 5;
    int c0 = (tb % 192) * 32;
    int k0 = (tb / 192) * 32;
    const float* W; _Float16* D; int Nw, cl;
    if (c0 < 3072)      { W = Wt; D = WtT; Nw = 3072; cl = c0; }
    else if (c0 < 5120) { W = Ws; D = WsT; Nw = 2048; cl = c0 - 3072; }
    else                { W = Wc; D = WcT; Nw = 1024; cl = c0 - 5120; }
#pragma unroll
    for (int j = 0; j < 4; ++j)
      T[ty + j * 8][tx] = W[(size_t)(k0 + ty + j * 8) * Nw + cl + tx];
    __syncthreads();
#pragma unroll
    for (int j = 0; j < 4; ++j)
      D[(size_t)(cl + ty + j * 8) * 1024 + k0 + tx] = (_Float16)T[tx][ty + j * 8];
  }
}

// ---------------------------------------------------------------------------
// Merged projection GEMM (R9 version, kept): BK=64 single-buffered,
// __launch_bounds__(256,3). Grid (16, 80).
// ---------------------------------------------------------------------------
__global__ __launch_bounds__(256, 3) void proj_gemm(
    const _Float16* __restrict__ xt16, const _Float16* __restrict__ xs16,
    const _Float16* __restrict__ WtT, const _Float16* __restrict__ WsT,
    const float* __restrict__ bt, const float* __restrict__ bs,
    _Float16* __restrict__ q16, _Float16* __restrict__ k16,
    _Float16* __restrict__ v16) {
  __shared__ _Float16 Al[128 * 64];
  __shared__ _Float16 Bl[128 * 64];

  const int tid = threadIdx.x;
  const int w = tid >> 6;
  const int lane = tid & 63;
  const int quad = lane >> 4;
  const int l15 = lane & 15;
  const int wm = w >> 1, wn = w & 1;
  const int by = blockIdx.y;
  const int n0 = blockIdx.x * 128;

  const _Float16* Ab;
  const _Float16* Bb;
  const float* bias;
  int m0, bsel = 0, branch;
  if (by < 32) {            // t-QK
    branch = 0; Ab = xt16; Bb = WtT; bias = bt; m0 = by * 128;
  } else if (by < 48) {     // V^T
    branch = 1;
    int by2 = by - 32;
    bsel = by2 >> 3;
    m0 = (by2 & 7) * 128;
    Ab = WtT + (size_t)2048 * 1024;
    Bb = xt16 + (size_t)bsel * 2048 * 1024;
    bias = bt;
  } else {                  // s-QK
    branch = 2; Ab = xs16; Bb = WsT; bias = bs; m0 = (by - 48) * 128;
  }

  const int srow = lane >> 3;
  const int sch = lane & 7;

  f32x4 acc[4][4];
#pragma unroll
  for (int mb = 0; mb < 4; ++mb)
#pragma unroll
    for (int nb = 0; nb < 4; ++nb) acc[mb][nb] = (f32x4){0.f, 0.f, 0.f, 0.f};

  for (int kt = 0; kt < 1024; kt += 64) {
    __syncthreads();
#pragma unroll
    for (int a = 0; a < 4; ++a) {
      int row = w * 32 + a * 8 + srow;
      int sc = sch ^ (row & 7);
      async_ld16(&Ab[(size_t)(m0 + row) * 1024 + kt + sc * 8], &Al[(w * 32 + a * 8) * 64]);
      async_ld16(&Bb[(size_t)(n0 + row) * 1024 + kt + sc * 8], &Bl[(w * 32 + a * 8) * 64]);
    }
    __syncthreads();

#pragma unroll
    for (int g = 0; g < 2; ++g) {
      f16x8 af[4], bf[4];
#pragma unroll
      for (int mb = 0; mb < 4; ++mb) {
        int row = wm * 64 + mb * 16 + l15;
        int pc = ((g * 4 + quad) ^ (row & 7)) * 8;
        af[mb] = *(const f16x8*)&Al[row * 64 + pc];
      }
#pragma unroll
      for (int nb = 0; nb < 4; ++nb) {
        int row = wn * 64 + nb * 16 + l15;
        int pc = ((g * 4 + quad) ^ (row & 7)) * 8;
        bf[nb] = *(const f16x8*)&Bl[row * 64 + pc];
      }
#pragma unroll
      for (int mb = 0; mb < 4; ++mb)
#pragma unroll
        for (int nb = 0; nb < 4; ++nb)
          acc[mb][nb] = __builtin_amdgcn_mfma_f32_16x16x32_f16(af[mb], bf[nb], acc[mb][nb], 0, 0, 0);
    }
  }

#pragma unroll
  for (int mb = 0; mb < 4; ++mb)
#pragma unroll
    for (int nb = 0; nb < 4; ++nb)
#pragma unroll
      for (int r = 0; r < 4; ++r) {
        int row = m0 + wm * 64 + mb * 16 + quad * 4 + r;
        int col = n0 + wn * 64 + nb * 16 + l15;
        if (branch == 1) {
          float val = acc[mb][nb][r] + bias[2048 + row];
          v16[(size_t)(bsel * 1024 + row) * 2048 + col] = (_Float16)val;
        } else {
          float val = acc[mb][nb][r] + bias[col];
          int bb = row >> 11, ll = row & 2047;
          int which = col >> 10, e = col & 1023;
          int hh = e >> 6, dd = e & 63;
          size_t rowhd = (size_t)(bb * 16 + hh) * 2048 + ll;
          int off = (branch == 0) ? 0 : 64;
          if (which == 0) q16[rowhd * 128 + off + dd] = (_Float16)val;
          else            k16[rowhd * 128 + off + dd] = (_Float16)val;
        }
      }
}

// ---------------------------------------------------------------------------
// c_proj GEMM (unchanged): 128x64 tiles, grid (16,32), dbuf BK=32.
// ---------------------------------------------------------------------------
__global__ __launch_bounds__(256) void cproj_gemm(
    const _Float16* __restrict__ A, const _Float16* __restrict__ Bm,
    const float* __restrict__ bias, float* __restrict__ outf) {
  __shared__ _Float16 Al0[128 * 32];
  __shared__ _Float16 Bl0[64 * 32];
  __shared__ _Float16 Al1[128 * 32];
  __shared__ _Float16 Bl1[64 * 32];

  const int tid = threadIdx.x;
  const int w = tid >> 6;
  const int lane = tid & 63;
  const int quad = lane >> 4;
  const int l15 = lane & 15;
  const int wm = w >> 1, wn = w & 1;
  const int m0 = blockIdx.y * 128;
  const int n0 = blockIdx.x * 64;

  const int srow = lane >> 2;
  const int schunk = ((lane & 3) ^ ((lane >> 3) & 3)) * 8;

  f32x4 acc[4][2];
#pragma unroll
  for (int mb = 0; mb < 4; ++mb)
#pragma unroll
    for (int nb = 0; nb < 2; ++nb) acc[mb][nb] = (f32x4){0.f, 0.f, 0.f, 0.f};

  const int key = (l15 >> 1) & 3;

  auto dma = [&](int kt, _Float16* Al, _Float16* Bl) {
#pragma unroll
    for (int i = 0; i < 2; ++i) {
      int rt = w * 32 + i * 16;
      async_ld16(&A[(size_t)(m0 + rt + srow) * 1024 + kt + schunk], &Al[rt * 32]);
    }
    int rtb = w * 16;
    async_ld16(&Bm[(size_t)(n0 + rtb + srow) * 1024 + kt + schunk], &Bl[rtb * 32]);
  };

  auto comp = [&](const _Float16* Al, const _Float16* Bl) {
    f16x8 af[4], bf[2];
    const int pc = (quad ^ key) * 8;
#pragma unroll
    for (int mb = 0; mb < 4; ++mb)
      af[mb] = *(const f16x8*)&Al[(wm * 64 + mb * 16 + l15) * 32 + pc];
#pragma unroll
    for (int nb = 0; nb < 2; ++nb)
      bf[nb] = *(const f16x8*)&Bl[(wn * 32 + nb * 16 + l15) * 32 + pc];
#pragma unroll
    for (int mb = 0; mb < 4; ++mb)
#pragma unroll
      for (int nb = 0; nb < 2; ++nb)
        acc[mb][nb] = __builtin_amdgcn_mfma_f32_16x16x32_f16(af[mb], bf[nb], acc[mb][nb], 0, 0, 0);
  };

  dma(0, Al0, Bl0);
  for (int kt = 0; kt < 1024; kt += 64) {
    __syncthreads();
    dma(kt + 32, Al1, Bl1);
    comp(Al0, Bl0);
    __syncthreads();
    if (kt + 64 < 1024) dma(kt + 64, Al0, Bl0);
    comp(Al1, Bl1);
  }

#pragma unroll
  for (int mb = 0; mb < 4; ++mb)
#pragma unroll
    for (int nb = 0; nb < 2; ++nb)
#pragma unroll
      for (int r = 0; r < 4; ++r) {
        int row = m0 + wm * 64 + mb * 16 + quad * 4 + r;
        int col = n0 + wn * 32 + nb * 16 + l15;
        outf[(size_t)row * 1024 + col] = acc[mb][nb][r] + bias[col];
      }
}

// ---------------------------------------------------------------------------
// MFMA flash attention v6: K fragments read DIRECTLY from global (L1/L2),
// no Ksh, no K DMA -- LDS port carries only V. The A-operand fragment
// K[kb*32+l31][db*16+half*8 .. +8] is a contiguous 16B global load.
// LDS: V dbuf only, 16 KB. V staged via swizzled global_load_lds as before.
// ---------------------------------------------------------------------------
__global__ __launch_bounds__(256, 2) void flash_attn_mfma(
    const _Float16* __restrict__ qcat, const _Float16* __restrict__ kcat,
    const _Float16* __restrict__ vT, _Float16* __restrict__ y,
    const float* __restrict__ lam_ts, const float* __restrict__ lam_st,
    const float* __restrict__ lam_ss) {
  const int bh = blockIdx.y;
  const int qt0 = blockIdx.x * 128;
  const int b = bh >> 4, h = bh & 15;
  const _Float16* Qg = qcat + (size_t)bh * LQ * 128;
  const _Float16* Kg = kcat + (size_t)bh * LQ * 128;
  const _Float16* Vg = vT + (size_t)bh * 64 * LQ;     // [dim][key]

  __shared__ _Float16 Vsh0[64 * 64];
  __shared__ _Float16 Vsh1[64 * 64];

  const int tid = threadIdx.x;
  const int w = tid >> 6;                    // wave 0..3
  const int lane = tid & 63;
  const int half = lane >> 5;                // 0/1
  const int l31 = lane & 31;

  const float lts = lam_ts[0], lst = lam_st[0], lss = lam_ss[0];

  // Q-combine into B-frags: wave w owns qrows qt0 + w*32 + [0,32)
  f16x8 qf[8];
#pragma unroll
  for (int db = 0; db < 4; ++db) {
    const _Float16* qp = &Qg[(size_t)(qt0 + w * 32 + l31) * 128 + db * 16 + half * 8];
    f16x8 a = *(const f16x8*)qp;          // qt dims
    f16x8 bq = *(const f16x8*)(qp + 64);  // qs dims
#pragma unroll
    for (int e = 0; e < 8; ++e) {
      float fa = (float)a[e], fb = (float)bq[e];
      qf[db][e]     = (_Float16)(QSCALE * (fa + lst * fb));
      qf[db + 4][e] = (_Float16)(QSCALE * (lts * fa + lss * fb));
    }
  }

  float m_i = -INFINITY;
  float l_i = 0.f;
  f32x16 O[2];
#pragma unroll
  for (int nt = 0; nt < 2; ++nt)
#pragma unroll
    for (int r = 0; r < 16; ++r) O[nt][r] = 0.f;

  // Per-lane K row pointers (kb = 0/1), advanced by t inside compute.
  const _Float16* kp0 = Kg + (size_t)l31 * 128 + half * 8;
  const _Float16* kp1 = Kg + (size_t)(32 + l31) * 128 + half * 8;

  auto dmaV = [&](int t, _Float16* Vd) {
#pragma unroll
    for (int a = 0; a < 2; ++a) {
      int row = w * 16 + a * 8 + (lane >> 3);          // dim
      int sc = (lane & 7) ^ (row & 7);
      async_ld16(&Vg[(size_t)row * LQ + t + sc * 8], &Vd[(w * 16 + a * 8) * 64]);
    }
  };

  auto compute = [&](int t, const _Float16* Vs) {
    // Prefetch K fragments from global (L1-resident tile, 4x wave reuse)
    f16x8 af[2][8];
    const _Float16* k0 = kp0 + (size_t)t * 128;
    const _Float16* k1 = kp1 + (size_t)t * 128;
#pragma unroll
    for (int db = 0; db < 8; ++db) {
      af[0][db] = *(const f16x8*)(k0 + db * 16);
      af[1][db] = *(const f16x8*)(k1 + db * 16);
    }

    // S^T[key][qrow]: 2 key-tiles of 32, contraction over 128 concat dims
    f32x16 S[2];
#pragma unroll
    for (int kb = 0; kb < 2; ++kb)
#pragma unroll
      for (int r = 0; r < 16; ++r) S[kb][r] = 0.f;
#pragma unroll
    for (int db = 0; db < 8; ++db)
#pragma unroll
      for (int kb = 0; kb < 2; ++kb)
        S[kb] = __builtin_amdgcn_mfma_f32_32x32x16_f16(af[kb][db], qf[db], S[kb], 0, 0, 0);

    // Online softmax (exp2 domain), lane-local qrow = l31.
    float mx = -INFINITY;
#pragma unroll
    for (int kb = 0; kb < 2; ++kb)
#pragma unroll
      for (int r = 0; r < 16; ++r) mx = fmaxf(mx, S[kb][r]);
    mx = fmaxf(mx, __shfl_xor(mx, 32));
    float m_new = fmaxf(m_i, mx);
    float alpha = __builtin_amdgcn_exp2f(m_i - m_new);
    float s = 0.f;
#pragma unroll
    for (int kb = 0; kb < 2; ++kb)
#pragma unroll
      for (int r = 0; r < 16; ++r) {
        float p = __builtin_amdgcn_exp2f(S[kb][r] - m_new);
        S[kb][r] = p;
        s += p;
      }
    s += __shfl_xor(s, 32);
    l_i = l_i * alpha + s;
    m_i = m_new;

#pragma unroll
    for (int nt = 0; nt < 2; ++nt)
#pragma unroll
      for (int r = 0; r < 16; ++r) O[nt][r] *= alpha;

    unsigned pu[2][8];
#pragma unroll
    for (int kb = 0; kb < 2; ++kb)
#pragma unroll
      for (int i = 0; i < 8; ++i) {
        f16x2 t2;
        t2[0] = (_Float16)S[kb][2 * i];
        t2[1] = (_Float16)S[kb][2 * i + 1];
        pu[kb][i] = __builtin_bit_cast(unsigned, t2);
      }

#pragma unroll
    for (int kb = 0; kb < 2; ++kb)
#pragma unroll
      for (int c = 0; c < 2; ++c) {
        unsigned ulo0 = pu[kb][4 * c + 0], ulo1 = pu[kb][4 * c + 1];
        unsigned uhi0 = pu[kb][4 * c + 2], uhi1 = pu[kb][4 * c + 3];
        unsigned rlo0 = (unsigned)__shfl_xor((int)ulo0, 32);
        unsigned rlo1 = (unsigned)__shfl_xor((int)ulo1, 32);
        unsigned rhi0 = (unsigned)__shfl_xor((int)uhi0, 32);
        unsigned rhi1 = (unsigned)__shfl_xor((int)uhi1, 32);
        union { unsigned u[4]; f16x8 v; } pb;
        pb.u[0] = half ? rhi0 : ulo0;
        pb.u[1] = half ? rhi1 : ulo1;
        pb.u[2] = half ? uhi0 : rlo0;
        pb.u[3] = half ? uhi1 : rlo1;
        int kb2 = kb * 2 + c;
        f16x8 av[2];
#pragma unroll
        for (int nt = 0; nt < 2; ++nt) {
          int dim = nt * 32 + l31;
          int pc = ((kb2 * 2 + half) ^ (dim & 7)) * 8;
          av[nt] = *(const f16x8*)&Vs[dim * 64 + pc];
        }
#pragma unroll
        for (int nt = 0; nt < 2; ++nt)
          O[nt] = __builtin_amdgcn_mfma_f32_32x32x16_f16(av[nt], pb.v, O[nt], 0, 0, 0);
      }
  };

  dmaV(0, Vsh0);
  for (int t = 0; t < LQ; t += 128) {
    __syncthreads();                 // drains dmaV(t)
    dmaV(t + 64, Vsh1);              // overlaps compute(t)
    compute(t, Vsh0);
    __syncthreads();                 // drains dmaV(t+64)
    if (t + 128 < LQ) dmaV(t + 128, Vsh0);
    compute(t + 64, Vsh1);
  }

  // Epilogue: lane-local 1/l; O^T row = dim, col = qrow (lane-local).
  float inv = 1.f / l_i;
  int qrow = qt0 + w * 32 + l31;
#pragma unroll
  for (int nt = 0; nt < 2; ++nt)
#pragma unroll
    for (int rg = 0; rg < 4; ++rg) {
      f16x4 o4;
#pragma unroll
      for (int i = 0; i < 4; ++i) o4[i] = (_Float16)(O[nt][rg * 4 + i] * inv);
      int dim = nt * 32 + rg * 8 + half * 4;
      *(f16x4*)&y[((size_t)b * LQ + qrow) * EQ + h * 64 + dim] = o4;
    }
}

// ---------------------------------------------------------------------------
extern "C" void kernel_launch(void* const* d_in, const int* in_sizes, int n_in,
                              void* d_out, int out_size, void* d_ws, size_t ws_size,
                              hipStream_t stream) {
  const float* xt = (const float*)d_in[0];
  const float* xs = (const float*)d_in[1];
  const float* Wt = (const float*)d_in[2];
  const float* bt = (const float*)d_in[3];
  const float* Ws = (const float*)d_in[4];
  const float* bs = (const float*)d_in[5];
  const float* Wc = (const float*)d_in[6];
  const float* bc = (const float*)d_in[7];
  const float* lam_ts = (const float*)d_in[8];
  const float* lam_st = (const float*)d_in[9];
  const float* lam_ss = (const float*)d_in[10];
  float* out = (float*)d_out;

  _Float16* w16 = (_Float16*)d_ws;
  _Float16* xt16 = w16;                       // 4,194,304
  _Float16* xs16 = xt16 + 4194304;            // 4,194,304
  _Float16* WtT  = xs16 + 4194304;            // 3,145,728
  _Float16* WsT  = WtT + 3145728;             // 2,097,152
  _Float16* WcT  = WsT + 2097152;             // 1,048,576
  _Float16* qcat = WcT + 1048576;             // 8,388,608  [bh][l][128] = [qt|qs]
  _Float16* kcat = qcat + 8388608;            // 8,388,608  [bh][l][128] = [kt|ks]
  _Float16* vbufT = kcat + 8388608;           // 4,194,304  [bh][dim][l]
  _Float16* ybuf = vbufT + 4194304;           // 4,194,304  [b*l][1024]

  prep<<<10240, 256, 0, stream>>>(xt, xs, Wt, Ws, Wc, xt16, xs16, WtT, WsT, WcT);
  proj_gemm<<<dim3(16, 80), 256, 0, stream>>>(
      xt16, xs16, WtT, WsT, bt, bs, qcat, kcat, vbufT);
  flash_attn_mfma<<<dim3(16, 32), 256, 0, stream>>>(
      qcat, kcat, vbufT, ybuf, lam_ts, lam_st, lam_ss);
  cproj_gemm<<<dim3(16, 32), 256, 0, stream>>>(ybuf, WcT, bc, out);
}

// Round 11
// 263.714 us; speedup vs baseline: 1.3492x; 1.3492x over previous
//
#include <hip/hip_runtime.h>
#include <math.h>

// Problem constants: B=2, L=2048, E=1024, H=16, D=64
#define LQ 2048
#define EQ 1024
#define M_ROWS 4096
#define BH 32

typedef _Float16 f16x8 __attribute__((ext_vector_type(8)));
typedef _Float16 f16x4 __attribute__((ext_vector_type(4)));
typedef _Float16 f16x2 __attribute__((ext_vector_type(2)));
typedef float f32x4 __attribute__((ext_vector_type(4)));
typedef float f32x16 __attribute__((ext_vector_type(16)));

// 1/sqrt(64) * log2(e) -> softmax in exp2 domain (applied to combined q)
#define QSCALE 0.1803368801111204f

__device__ __forceinline__ void async_ld16(const _Float16* g, _Float16* l) {
  __builtin_amdgcn_global_load_lds(
      (const __attribute__((address_space(1))) unsigned int*)g,
      (__attribute__((address_space(3))) unsigned int*)l, 16, 0, 0);
}

// ---------------------------------------------------------------------------
// Prep (1 launch): blocks [0,4096) convert xt,xs fp32->fp16;
// blocks [4096,7168) transpose W fp32[k][n] -> WT fp16[n][k] in 32k x 64c
// tiles, float2 loads, f16x2 stores (64B contiguous per 16-lane group).
// ---------------------------------------------------------------------------
__global__ __launch_bounds__(256) void prep(
    const float* __restrict__ xt, const float* __restrict__ xs,
    const float* __restrict__ Wt, const float* __restrict__ Ws,
    const float* __restrict__ Wc,
    _Float16* __restrict__ xt16, _Float16* __restrict__ xs16,
    _Float16* __restrict__ WtT, _Float16* __restrict__ WsT,
    _Float16* __restrict__ WcT) {
  int gb = blockIdx.x;
  if (gb < 4096) {
    int i = gb * 256 + threadIdx.x;
    const float* s; _Float16* d; size_t off;
    if (i < 524288) { s = xt; d = xt16; off = (size_t)i * 8; }
    else            { s = xs; d = xs16; off = (size_t)(i - 524288) * 8; }
    float4 a = *(const float4*)&s[off];
    float4 b = *(const float4*)&s[off + 4];
    f16x8 h;
    h[0] = (_Float16)a.x; h[1] = (_Float16)a.y; h[2] = (_Float16)a.z; h[3] = (_Float16)a.w;
    h[4] = (_Float16)b.x; h[5] = (_Float16)b.y; h[6] = (_Float16)b.z; h[7] = (_Float16)b.w;
    *(f16x8*)&d[off] = h;
  } else {
    __shared__ float T[32][65];
    int tb = gb - 4096;                 // 0..3071
    int c0 = (tb % 96) * 64;            // global col tile over 6144
    int k0 = (tb / 96) * 32;            // k tile over 1024
    const float* W; _Float16* D; int Nw, cl;
    if (c0 < 3072)      { W = Wt; D = WtT; Nw = 3072; cl = c0; }
    else if (c0 < 5120) { W = Ws; D = WsT; Nw = 2048; cl = c0 - 3072; }
    else                { W = Wc; D = WcT; Nw = 1024; cl = c0 - 5120; }
    const int tid = threadIdx.x;
    // Load: 32 rows x 64 cols = 1024 float2; 4 per thread
#pragma unroll
    for (int p = 0; p < 4; ++p) {
      int idx = tid + p * 256;
      int row = idx >> 5;               // 0..31
      int c2 = (idx & 31) * 2;          // 0..62
      float2 v = *(const float2*)&W[(size_t)(k0 + row) * Nw + cl + c2];
      T[row][c2] = v.x;
      T[row][c2 + 1] = v.y;
    }
    __syncthreads();
    // Store: 64 cols x 16 k-pairs = 1024 f16x2; 4 per thread
#pragma unroll
    for (int p = 0; p < 4; ++p) {
      int idx = tid + p * 256;
      int col = idx >> 4;               // 0..63
      int k2 = (idx & 15) * 2;          // 0..30
      f16x2 h2;
      h2[0] = (_Float16)T[k2][col];
      h2[1] = (_Float16)T[k2 + 1][col];
      *(f16x2*)&D[(size_t)(cl + col) * 1024 + k0 + k2] = h2;
    }
  }
}

// ---------------------------------------------------------------------------
// Merged projection GEMM (R9 version, kept): BK=64 single-buffered,
// __launch_bounds__(256,3). Grid (16, 80).
// ---------------------------------------------------------------------------
__global__ __launch_bounds__(256, 3) void proj_gemm(
    const _Float16* __restrict__ xt16, const _Float16* __restrict__ xs16,
    const _Float16* __restrict__ WtT, const _Float16* __restrict__ WsT,
    const float* __restrict__ bt, const float* __restrict__ bs,
    _Float16* __restrict__ q16, _Float16* __restrict__ k16,
    _Float16* __restrict__ v16) {
  __shared__ _Float16 Al[128 * 64];
  __shared__ _Float16 Bl[128 * 64];

  const int tid = threadIdx.x;
  const int w = tid >> 6;
  const int lane = tid & 63;
  const int quad = lane >> 4;
  const int l15 = lane & 15;
  const int wm = w >> 1, wn = w & 1;
  const int by = blockIdx.y;
  const int n0 = blockIdx.x * 128;

  const _Float16* Ab;
  const _Float16* Bb;
  const float* bias;
  int m0, bsel = 0, branch;
  if (by < 32) {            // t-QK
    branch = 0; Ab = xt16; Bb = WtT; bias = bt; m0 = by * 128;
  } else if (by < 48) {     // V^T
    branch = 1;
    int by2 = by - 32;
    bsel = by2 >> 3;
    m0 = (by2 & 7) * 128;
    Ab = WtT + (size_t)2048 * 1024;
    Bb = xt16 + (size_t)bsel * 2048 * 1024;
    bias = bt;
  } else {                  // s-QK
    branch = 2; Ab = xs16; Bb = WsT; bias = bs; m0 = (by - 48) * 128;
  }

  const int srow = lane >> 3;
  const int sch = lane & 7;

  f32x4 acc[4][4];
#pragma unroll
  for (int mb = 0; mb < 4; ++mb)
#pragma unroll
    for (int nb = 0; nb < 4; ++nb) acc[mb][nb] = (f32x4){0.f, 0.f, 0.f, 0.f};

  for (int kt = 0; kt < 1024; kt += 64) {
    __syncthreads();
#pragma unroll
    for (int a = 0; a < 4; ++a) {
      int row = w * 32 + a * 8 + srow;
      int sc = sch ^ (row & 7);
      async_ld16(&Ab[(size_t)(m0 + row) * 1024 + kt + sc * 8], &Al[(w * 32 + a * 8) * 64]);
      async_ld16(&Bb[(size_t)(n0 + row) * 1024 + kt + sc * 8], &Bl[(w * 32 + a * 8) * 64]);
    }
    __syncthreads();

#pragma unroll
    for (int g = 0; g < 2; ++g) {
      f16x8 af[4], bf[4];
#pragma unroll
      for (int mb = 0; mb < 4; ++mb) {
        int row = wm * 64 + mb * 16 + l15;
        int pc = ((g * 4 + quad) ^ (row & 7)) * 8;
        af[mb] = *(const f16x8*)&Al[row * 64 + pc];
      }
#pragma unroll
      for (int nb = 0; nb < 4; ++nb) {
        int row = wn * 64 + nb * 16 + l15;
        int pc = ((g * 4 + quad) ^ (row & 7)) * 8;
        bf[nb] = *(const f16x8*)&Bl[row * 64 + pc];
      }
#pragma unroll
      for (int mb = 0; mb < 4; ++mb)
#pragma unroll
        for (int nb = 0; nb < 4; ++nb)
          acc[mb][nb] = __builtin_amdgcn_mfma_f32_16x16x32_f16(af[mb], bf[nb], acc[mb][nb], 0, 0, 0);
    }
  }

#pragma unroll
  for (int mb = 0; mb < 4; ++mb)
#pragma unroll
    for (int nb = 0; nb < 4; ++nb)
#pragma unroll
      for (int r = 0; r < 4; ++r) {
        int row = m0 + wm * 64 + mb * 16 + quad * 4 + r;
        int col = n0 + wn * 64 + nb * 16 + l15;
        if (branch == 1) {
          float val = acc[mb][nb][r] + bias[2048 + row];
          v16[(size_t)(bsel * 1024 + row) * 2048 + col] = (_Float16)val;
        } else {
          float val = acc[mb][nb][r] + bias[col];
          int bb = row >> 11, ll = row & 2047;
          int which = col >> 10, e = col & 1023;
          int hh = e >> 6, dd = e & 63;
          size_t rowhd = (size_t)(bb * 16 + hh) * 2048 + ll;
          int off = (branch == 0) ? 0 : 64;
          if (which == 0) q16[rowhd * 128 + off + dd] = (_Float16)val;
          else            k16[rowhd * 128 + off + dd] = (_Float16)val;
        }
      }
}

// ---------------------------------------------------------------------------
// c_proj GEMM: 128x64 tiles, grid (16,32), dbuf BK=32, launch_bounds(256,3)
// (acc 32 AGPR + ~84 VGPR = ~116 <= 170 -> 3 waves/SIMD fits).
// ---------------------------------------------------------------------------
__global__ __launch_bounds__(256, 3) void cproj_gemm(
    const _Float16* __restrict__ A, const _Float16* __restrict__ Bm,
    const float* __restrict__ bias, float* __restrict__ outf) {
  __shared__ _Float16 Al0[128 * 32];
  __shared__ _Float16 Bl0[64 * 32];
  __shared__ _Float16 Al1[128 * 32];
  __shared__ _Float16 Bl1[64 * 32];

  const int tid = threadIdx.x;
  const int w = tid >> 6;
  const int lane = tid & 63;
  const int quad = lane >> 4;
  const int l15 = lane & 15;
  const int wm = w >> 1, wn = w & 1;
  const int m0 = blockIdx.y * 128;
  const int n0 = blockIdx.x * 64;

  const int srow = lane >> 2;
  const int schunk = ((lane & 3) ^ ((lane >> 3) & 3)) * 8;

  f32x4 acc[4][2];
#pragma unroll
  for (int mb = 0; mb < 4; ++mb)
#pragma unroll
    for (int nb = 0; nb < 2; ++nb) acc[mb][nb] = (f32x4){0.f, 0.f, 0.f, 0.f};

  const int key = (l15 >> 1) & 3;

  auto dma = [&](int kt, _Float16* Al, _Float16* Bl) {
#pragma unroll
    for (int i = 0; i < 2; ++i) {
      int rt = w * 32 + i * 16;
      async_ld16(&A[(size_t)(m0 + rt + srow) * 1024 + kt + schunk], &Al[rt * 32]);
    }
    int rtb = w * 16;
    async_ld16(&Bm[(size_t)(n0 + rtb + srow) * 1024 + kt + schunk], &Bl[rtb * 32]);
  };

  auto comp = [&](const _Float16* Al, const _Float16* Bl) {
    f16x8 af[4], bf[2];
    const int pc = (quad ^ key) * 8;
#pragma unroll
    for (int mb = 0; mb < 4; ++mb)
      af[mb] = *(const f16x8*)&Al[(wm * 64 + mb * 16 + l15) * 32 + pc];
#pragma unroll
    for (int nb = 0; nb < 2; ++nb)
      bf[nb] = *(const f16x8*)&Bl[(wn * 32 + nb * 16 + l15) * 32 + pc];
#pragma unroll
    for (int mb = 0; mb < 4; ++mb)
#pragma unroll
      for (int nb = 0; nb < 2; ++nb)
        acc[mb][nb] = __builtin_amdgcn_mfma_f32_16x16x32_f16(af[mb], bf[nb], acc[mb][nb], 0, 0, 0);
  };

  dma(0, Al0, Bl0);
  for (int kt = 0; kt < 1024; kt += 64) {
    __syncthreads();
    dma(kt + 32, Al1, Bl1);
    comp(Al0, Bl0);
    __syncthreads();
    if (kt + 64 < 1024) dma(kt + 64, Al0, Bl0);
    comp(Al1, Bl1);
  }

#pragma unroll
  for (int mb = 0; mb < 4; ++mb)
#pragma unroll
    for (int nb = 0; nb < 2; ++nb)
#pragma unroll
      for (int r = 0; r < 4; ++r) {
        int row = m0 + wm * 64 + mb * 16 + quad * 4 + r;
        int col = n0 + wn * 32 + nb * 16 + l15;
        outf[(size_t)row * 1024 + col] = acc[mb][nb][r] + bias[col];
      }
}

// ---------------------------------------------------------------------------
// MFMA flash attention (REVERTED to R9's verified v5): 32x32x16, O^T form,
// K+V staged in LDS via swizzled global_load_lds, dbuf, q-combine on load,
// P via shfl_xor(32) register exchange. (R10's direct-global K read regressed
// 2x: row-scattered per-lane loads serialize on L1 tag lookups — LDS staging
// via wave-uniform DMA is the right operand-fetch path. Keep Ksh.)
// ---------------------------------------------------------------------------
__global__ __launch_bounds__(256, 2) void flash_attn_mfma(
    const _Float16* __restrict__ qcat, const _Float16* __restrict__ kcat,
    const _Float16* __restrict__ vT, _Float16* __restrict__ y,
    const float* __restrict__ lam_ts, const float* __restrict__ lam_st,
    const float* __restrict__ lam_ss) {
  const int bh = blockIdx.y;
  const int qt0 = blockIdx.x * 128;
  const int b = bh >> 4, h = bh & 15;
  const _Float16* Qg = qcat + (size_t)bh * LQ * 128;
  const _Float16* Kg = kcat + (size_t)bh * LQ * 128;
  const _Float16* Vg = vT + (size_t)bh * 64 * LQ;     // [dim][key]

  __shared__ _Float16 Ksh0[64 * 128];
  __shared__ _Float16 Ksh1[64 * 128];
  __shared__ _Float16 Vsh0[64 * 64];
  __shared__ _Float16 Vsh1[64 * 64];

  const int tid = threadIdx.x;
  const int w = tid >> 6;                    // wave 0..3
  const int lane = tid & 63;
  const int half = lane >> 5;                // 0/1
  const int l31 = lane & 31;

  const float lts = lam_ts[0], lst = lam_st[0], lss = lam_ss[0];

  // Q-combine into B-frags: wave w owns qrows qt0 + w*32 + [0,32)
  f16x8 qf[8];
#pragma unroll
  for (int db = 0; db < 4; ++db) {
    const _Float16* qp = &Qg[(size_t)(qt0 + w * 32 + l31) * 128 + db * 16 + half * 8];
    f16x8 a = *(const f16x8*)qp;          // qt dims
    f16x8 bq = *(const f16x8*)(qp + 64);  // qs dims
#pragma unroll
    for (int e = 0; e < 8; ++e) {
      float fa = (float)a[e], fb = (float)bq[e];
      qf[db][e]     = (_Float16)(QSCALE * (fa + lst * fb));
      qf[db + 4][e] = (_Float16)(QSCALE * (lts * fa + lss * fb));
    }
  }

  float m_i = -INFINITY;
  float l_i = 0.f;
  f32x16 O[2];
#pragma unroll
  for (int nt = 0; nt < 2; ++nt)
#pragma unroll
    for (int r = 0; r < 16; ++r) O[nt][r] = 0.f;

  auto dma = [&](int t, _Float16* Kd, _Float16* Vd) {
#pragma unroll
    for (int a = 0; a < 4; ++a) {
      int row = w * 16 + a * 4 + (lane >> 4);
      int sc = (lane & 15) ^ (row & 7);
      async_ld16(&Kg[(size_t)(t + row) * 128 + sc * 8], &Kd[(w * 16 + a * 4) * 128]);
    }
#pragma unroll
    for (int a = 0; a < 2; ++a) {
      int row = w * 16 + a * 8 + (lane >> 3);          // dim
      int sc = (lane & 7) ^ (row & 7);
      async_ld16(&Vg[(size_t)row * LQ + t + sc * 8], &Vd[(w * 16 + a * 8) * 64]);
    }
  };

  auto compute = [&](const _Float16* Ks, const _Float16* Vs) {
    f32x16 S[2];
#pragma unroll
    for (int kb = 0; kb < 2; ++kb)
#pragma unroll
      for (int r = 0; r < 16; ++r) S[kb][r] = 0.f;
#pragma unroll
    for (int db = 0; db < 8; ++db) {
      const int pc = ((db * 2 + half) ^ (lane & 7)) * 8;
      f16x8 af[2];
#pragma unroll
      for (int kb = 0; kb < 2; ++kb)
        af[kb] = *(const f16x8*)&Ks[(kb * 32 + l31) * 128 + pc];
#pragma unroll
      for (int kb = 0; kb < 2; ++kb)
        S[kb] = __builtin_amdgcn_mfma_f32_32x32x16_f16(af[kb], qf[db], S[kb], 0, 0, 0);
    }

    float mx = -INFINITY;
#pragma unroll
    for (int kb = 0; kb < 2; ++kb)
#pragma unroll
      for (int r = 0; r < 16; ++r) mx = fmaxf(mx, S[kb][r]);
    mx = fmaxf(mx, __shfl_xor(mx, 32));
    float m_new = fmaxf(m_i, mx);
    float alpha = __builtin_amdgcn_exp2f(m_i - m_new);
    float s = 0.f;
#pragma unroll
    for (int kb = 0; kb < 2; ++kb)
#pragma unroll
      for (int r = 0; r < 16; ++r) {
        float p = __builtin_amdgcn_exp2f(S[kb][r] - m_new);
        S[kb][r] = p;
        s += p;
      }
    s += __shfl_xor(s, 32);
    l_i = l_i * alpha + s;
    m_i = m_new;

#pragma unroll
    for (int nt = 0; nt < 2; ++nt)
#pragma unroll
      for (int r = 0; r < 16; ++r) O[nt][r] *= alpha;

    unsigned pu[2][8];
#pragma unroll
    for (int kb = 0; kb < 2; ++kb)
#pragma unroll
      for (int i = 0; i < 8; ++i) {
        f16x2 t2;
        t2[0] = (_Float16)S[kb][2 * i];
        t2[1] = (_Float16)S[kb][2 * i + 1];
        pu[kb][i] = __builtin_bit_cast(unsigned, t2);
      }

#pragma unroll
    for (int kb = 0; kb < 2; ++kb)
#pragma unroll
      for (int c = 0; c < 2; ++c) {
        unsigned ulo0 = pu[kb][4 * c + 0], ulo1 = pu[kb][4 * c + 1];
        unsigned uhi0 = pu[kb][4 * c + 2], uhi1 = pu[kb][4 * c + 3];
        unsigned rlo0 = (unsigned)__shfl_xor((int)ulo0, 32);
        unsigned rlo1 = (unsigned)__shfl_xor((int)ulo1, 32);
        unsigned rhi0 = (unsigned)__shfl_xor((int)uhi0, 32);
        unsigned rhi1 = (unsigned)__shfl_xor((int)uhi1, 32);
        union { unsigned u[4]; f16x8 v; } pb;
        pb.u[0] = half ? rhi0 : ulo0;
        pb.u[1] = half ? rhi1 : ulo1;
        pb.u[2] = half ? uhi0 : rlo0;
        pb.u[3] = half ? uhi1 : rlo1;
        int kb2 = kb * 2 + c;
        f16x8 av[2];
#pragma unroll
        for (int nt = 0; nt < 2; ++nt) {
          int dim = nt * 32 + l31;
          int pc = ((kb2 * 2 + half) ^ (dim & 7)) * 8;
          av[nt] = *(const f16x8*)&Vs[dim * 64 + pc];
        }
#pragma unroll
        for (int nt = 0; nt < 2; ++nt)
          O[nt] = __builtin_amdgcn_mfma_f32_32x32x16_f16(av[nt], pb.v, O[nt], 0, 0, 0);
      }
  };

  dma(0, Ksh0, Vsh0);
  for (int t = 0; t < LQ; t += 128) {
    __syncthreads();
    dma(t + 64, Ksh1, Vsh1);
    compute(Ksh0, Vsh0);
    __syncthreads();
    if (t + 128 < LQ) dma(t + 128, Ksh0, Vsh0);
    compute(Ksh1, Vsh1);
  }

  float inv = 1.f / l_i;
  int qrow = qt0 + w * 32 + l31;
#pragma unroll
  for (int nt = 0; nt < 2; ++nt)
#pragma unroll
    for (int rg = 0; rg < 4; ++rg) {
      f16x4 o4;
#pragma unroll
      for (int i = 0; i < 4; ++i) o4[i] = (_Float16)(O[nt][rg * 4 + i] * inv);
      int dim = nt * 32 + rg * 8 + half * 4;
      *(f16x4*)&y[((size_t)b * LQ + qrow) * EQ + h * 64 + dim] = o4;
    }
}

// ---------------------------------------------------------------------------
extern "C" void kernel_launch(void* const* d_in, const int* in_sizes, int n_in,
                              void* d_out, int out_size, void* d_ws, size_t ws_size,
                              hipStream_t stream) {
  const float* xt = (const float*)d_in[0];
  const float* xs = (const float*)d_in[1];
  const float* Wt = (const float*)d_in[2];
  const float* bt = (const float*)d_in[3];
  const float* Ws = (const float*)d_in[4];
  const float* bs = (const float*)d_in[5];
  const float* Wc = (const float*)d_in[6];
  const float* bc = (const float*)d_in[7];
  const float* lam_ts = (const float*)d_in[8];
  const float* lam_st = (const float*)d_in[9];
  const float* lam_ss = (const float*)d_in[10];
  float* out = (float*)d_out;

  _Float16* w16 = (_Float16*)d_ws;
  _Float16* xt16 = w16;                       // 4,194,304
  _Float16* xs16 = xt16 + 4194304;            // 4,194,304
  _Float16* WtT  = xs16 + 4194304;            // 3,145,728
  _Float16* WsT  = WtT + 3145728;             // 2,097,152
  _Float16* WcT  = WsT + 2097152;             // 1,048,576
  _Float16* qcat = WcT + 1048576;             // 8,388,608  [bh][l][128] = [qt|qs]
  _Float16* kcat = qcat + 8388608;            // 8,388,608  [bh][l][128] = [kt|ks]
  _Float16* vbufT = kcat + 8388608;           // 4,194,304  [bh][dim][l]
  _Float16* ybuf = vbufT + 4194304;           // 4,194,304  [b*l][1024]

  prep<<<7168, 256, 0, stream>>>(xt, xs, Wt, Ws, Wc, xt16, xs16, WtT, WsT, WcT);
  proj_gemm<<<dim3(16, 80), 256, 0, stream>>>(
      xt16, xs16, WtT, WsT, bt, bs, qcat, kcat, vbufT);
  flash_attn_mfma<<<dim3(16, 32), 256, 0, stream>>>(
      qcat, kcat, vbufT, ybuf, lam_ts, lam_st, lam_ss);
  cproj_gemm<<<dim3(16, 32), 256, 0, stream>>>(ybuf, WcT, bc, out);
}